// Round 1
// 158.104 us; speedup vs baseline: 1.0063x; 1.0063x over previous
//
#include <hip/hip_runtime.h>
#include <cstdint>
#include <cstddef>

#define T_LEN 4096
#define S_DIM 308
#define S_PAD 320
#define E_DIM 126
#define NBATCH 32
#define NCHUNK 128
#define CHL 32
#define WARM 6     // contraction ~0.066/step -> ~1e-6 relative after warm-up
#define FH 136     // inH row stride (f16): 272B/row = 68 dw = 4 (mod 32) -> uniform banks
#define QSTR 336   // QL row stride (f16): 672B/row = 168 dw = 8 (mod 32) -> uniform b128
#define TC 16      // emis_pack timesteps per block

typedef _Float16 half8 __attribute__((ext_vector_type(8)));
typedef _Float16 half4 __attribute__((ext_vector_type(4)));
typedef float floatx4 __attribute__((ext_vector_type(4)));

union HU8 { uint4 u; half8 h; };
union HU4 { uint2 u; half4 h; };
union HU1 { uint16_t u; _Float16 h; };

__device__ __forceinline__ half8 h8_from_u4(uint4 v) { HU8 t; t.u = v; return t.h; }
__device__ __forceinline__ half4 h4_from_u2(uint2 v) { HU4 t; t.u = v; return t.h; }

// ---- merged init: blocks 0..49 pack A-frags, 50..69 pack B-frags, 70 zeroes out ----
// A-frag: tile = nt*10 + kt; lane l holds A[k=kt*32+(l>>4)*8+j][n=nt*16+(l&15)], j=0..7.
// In the transposed pipeline this same data serves as the MFMA *A*-operand for
// P^T = A^T @ Q^T (m = out-state on l&15, k = in-state on quad*8+j).
// B-frag: tile = nt*4 + kt over E padded to 128, value = 128*B[n][k]; serves as the
// A-operand for E^T = Bmat @ inp^T in emis_pack.
__global__ __launch_bounds__(256) void init_pack(const float* __restrict__ A,
                                                 const float* __restrict__ Bm,
                                                 uint32_t* __restrict__ Apk,
                                                 uint32_t* __restrict__ Bfr,
                                                 float* __restrict__ out) {
  int blk = blockIdx.x, tid = threadIdx.x;
  if (blk < 50) {
    int idx = blk * 256 + tid;                 // 200 tiles * 64 lanes
    int lane = idx & 63, tile = idx >> 6;
    int kt = tile % 10, nt = tile / 10;
    int n  = nt * 16 + (lane & 15);
    int k0 = kt * 32 + (lane >> 4) * 8;
    uint32_t wv[4];
#pragma unroll
    for (int jj = 0; jj < 4; jj++) {
      int ka = k0 + 2 * jj, kb = ka + 1;
      float x0 = (n < S_DIM && ka < S_DIM) ? A[ka * S_DIM + n] : 0.f;
      float x1 = (n < S_DIM && kb < S_DIM) ? A[kb * S_DIM + n] : 0.f;
      HU1 h0, h1; h0.h = (_Float16)x0; h1.h = (_Float16)x1;
      wv[jj] = (uint32_t)h0.u | ((uint32_t)h1.u << 16);
    }
    uint4 o; o.x = wv[0]; o.y = wv[1]; o.z = wv[2]; o.w = wv[3];
    ((uint4*)Apk)[idx] = o;
  } else if (blk < 70) {
    int idx = (blk - 50) * 256 + tid;          // 80 tiles * 64 lanes
    int lane = idx & 63, tile = idx >> 6;
    int kt = tile % 4, nt = tile / 4;
    int n  = nt * 16 + (lane & 15);
    int k0 = kt * 32 + (lane >> 4) * 8;
    uint32_t wv[4];
#pragma unroll
    for (int jj = 0; jj < 4; jj++) {
      int ka = k0 + 2 * jj, kb = ka + 1;
      float x0 = (n < S_DIM && ka < E_DIM) ? 128.f * Bm[n * E_DIM + ka] : 0.f;
      float x1 = (n < S_DIM && kb < E_DIM) ? 128.f * Bm[n * E_DIM + kb] : 0.f;
      HU1 h0, h1; h0.h = (_Float16)x0; h1.h = (_Float16)x1;
      wv[jj] = (uint32_t)h0.u | ((uint32_t)h1.u << 16);
    }
    uint4 o; o.x = wv[0]; o.y = wv[1]; o.z = wv[2]; o.w = wv[3];
    ((uint4*)Bfr)[idx] = o;
  } else {
    if (tid < NBATCH) out[tid] = 0.f;
  }
}

// ---- E precompute: E^T[t] fragments in main-loop register layout ----
// E^T = (128*Bmat) @ inp^T per t. Grid (T/TC, 2 batch-groups), 256 thr = 4 waves
// x 5 tiles. D C-layout: col = lane&15 = batch, row = quad*4+r = state-in-tile.
// Lane packs its 4 f32 -> 4 f16 -> one uint2, stored at
// Efrag[(t*40 + bg*20 + nt)*64 + lane]  (512B fully-coalesced per wave-store).
__global__ __launch_bounds__(256, 2)
void emis_pack(const uint32_t* __restrict__ Bfr, const float* __restrict__ inp,
               uint2* __restrict__ Efrag) {
  __shared__ __attribute__((aligned(16))) _Float16 inH[2][16 * FH];
  int tc = blockIdx.x, bg = blockIdx.y, bbase = bg * 16;
  int tid = threadIdx.x, lane = tid & 63, w = tid >> 6;
  int gl = lane & 15, quad = lane >> 4;

  half8 bfB[5][4];
#pragma unroll
  for (int q = 0; q < 5; q++)
#pragma unroll
    for (int kt = 0; kt < 4; kt++)
      bfB[q][kt] = h8_from_u4(((const uint4*)Bfr)[((w * 5 + q) * 4 + kt) * 64 + lane]);
#pragma unroll
  for (int q = 0; q < 5; q++)
#pragma unroll
    for (int kt = 0; kt < 4; kt++) asm volatile("" : "+v"(bfB[q][kt]));

  int t0 = tc * TC;
  // stage inH[0] <- rows at t0; 1024 u32 slots: r = flat>>6, c2 = flat&63 (c2==63 zero-fills)
#pragma unroll
  for (int s = 0; s < 4; s++) {
    int flat = tid + s * 256;
    int r = flat >> 6, c2 = flat & 63;
    float2 v; v.x = 0.f; v.y = 0.f;
    if (c2 < 63) v = *(const float2*)(inp + ((size_t)(bbase + r) * T_LEN + t0) * E_DIM + 2 * c2);
    HU1 a, b; a.h = (_Float16)v.x; b.h = (_Float16)v.y;
    *(uint32_t*)&inH[0][r * FH + 2 * c2] = (uint32_t)a.u | ((uint32_t)b.u << 16);
  }
  float2 g[4];   // prefetch t0+1
#pragma unroll
  for (int s = 0; s < 4; s++) {
    int flat = tid + s * 256;
    int r = flat >> 6, c2 = flat & 63;
    g[s].x = 0.f; g[s].y = 0.f;
    if (c2 < 63) g[s] = *(const float2*)(inp + ((size_t)(bbase + r) * T_LEN + (t0 + 1)) * E_DIM + 2 * c2);
  }
  __syncthreads();

  for (int i = 0; i < TC; i++) {
    int cur = i & 1, t = t0 + i;
    floatx4 Ea[5];
#pragma unroll
    for (int q = 0; q < 5; q++) Ea[q] = (floatx4){0.f, 0.f, 0.f, 0.f};
#pragma unroll
    for (int kt = 0; kt < 4; kt++) {
      half8 af = h8_from_u4(*(const uint4*)&inH[cur][gl * FH + kt * 32 + quad * 8]);
#pragma unroll
      for (int q = 0; q < 5; q++)
        Ea[q] = __builtin_amdgcn_mfma_f32_16x16x32_f16(bfB[q][kt], af, Ea[q], 0, 0, 0);
    }
    if (i < TC - 1) {
      // commit prefetched rows (t0+i+1) -> inH[cur^1]
#pragma unroll
      for (int s = 0; s < 4; s++) {
        int flat = tid + s * 256;
        int r = flat >> 6, c2 = flat & 63;
        HU1 a, b; a.h = (_Float16)g[s].x; b.h = (_Float16)g[s].y;
        uint32_t pv = (c2 < 63) ? ((uint32_t)a.u | ((uint32_t)b.u << 16)) : 0u;
        *(uint32_t*)&inH[cur ^ 1][r * FH + 2 * c2] = pv;
      }
      int tp = t0 + i + 2; if (tp > T_LEN - 1) tp = T_LEN - 1;
#pragma unroll
      for (int s = 0; s < 4; s++) {
        int flat = tid + s * 256;
        int r = flat >> 6, c2 = flat & 63;
        g[s].x = 0.f; g[s].y = 0.f;
        if (c2 < 63) g[s] = *(const float2*)(inp + ((size_t)(bbase + r) * T_LEN + tp) * E_DIM + 2 * c2);
      }
    }
#pragma unroll
    for (int q = 0; q < 5; q++) {
      HU1 h0, h1, h2, h3;
      h0.h = (_Float16)Ea[q][0]; h1.h = (_Float16)Ea[q][1];
      h2.h = (_Float16)Ea[q][2]; h3.h = (_Float16)Ea[q][3];
      uint2 o; o.x = (uint32_t)h0.u | ((uint32_t)h1.u << 16);
      o.y = (uint32_t)h2.u | ((uint32_t)h3.u << 16);
      Efrag[((size_t)t * 40 + bg * 20 + (w * 5 + q)) * 64 + lane] = o;
    }
    __syncthreads();
  }
}

// ---- transposed fused recursion, round-3: ----
// State-major: P^T[s][b], lane (quad,gl) holds states quad*4+r of its tiles for
// batch gl. 320 thr = 5 waves x 4 state-tiles (halves the per-step QL read
// traffic vs 10x2). Per step:
//   a) Q = P (.) E with E straight from Efrag registers (depth-2 prefetch, no
//      LDS, no E-MFMA); pack 4 consecutive states -> ONE ds_write_b64 per tile;
//   b) ONE barrier; P^T = A^T @ Q^T: 10x ds_read_b128 feeding 4 independent
//      MFMA chains. loglik telescopes between 2 checkpoint z-sums as before.
__global__ __launch_bounds__(320, 2)
void hmm_fused2(const uint32_t* __restrict__ Apk, const uint2* __restrict__ Efrag,
                const float* __restrict__ Ivec, float* __restrict__ out) {
  __shared__ __attribute__((aligned(16))) _Float16 QL[2][16 * QSTR];
  __shared__ float zslot[16];
  int c = blockIdx.x, bg = blockIdx.y, bbase = bg * 16;
  int tid = threadIdx.x, lane = tid & 63, w = tid >> 6;
  int gl = lane & 15, quad = lane >> 4;

  half8 bfA[4][10];
#pragma unroll
  for (int q = 0; q < 4; q++)
#pragma unroll
    for (int kt = 0; kt < 10; kt++)
      bfA[q][kt] = h8_from_u4(((const uint4*)Apk)[((w * 4 + q) * 10 + kt) * 64 + lane]);
#pragma unroll
  for (int q = 0; q < 4; q++)
#pragma unroll
    for (int kt = 0; kt < 10; kt++) asm volatile("" : "+v"(bfA[q][kt]));

  // P init, state-major: lane's value depends on its 4 states
  float Pa[4][4];
#pragma unroll
  for (int q = 0; q < 4; q++) {
    int sb = (w * 4 + q) * 16 + quad * 4;
#pragma unroll
    for (int r = 0; r < 4; r++) {
      int s = sb + r;
      Pa[q][r] = (s < S_DIM) ? (c == 0 ? Ivec[s] : 1.0f) : 0.f;
    }
  }
  if (tid < 16) zslot[tid] = 0.f;

  int t_first = (c == 0) ? 1 : (c * CHL - WARM + 1);
  int nstep   = (c == 0) ? (CHL - 1) : (CHL + WARM - 1);   // 31 or 37 (both odd)
  int iw      = (c == 0) ? -1 : (WARM - 1);                // z at t = c*CHL-1 (odd)
  int t_last  = t_first - 1 + nstep;

  // Efrag element index for this lane: t*2560 + ebase + q*64
  size_t ebase = (size_t)bg * 1280 + (size_t)(w * 4) * 64 + lane;
  uint2 ebA[4], ebB[4];
#pragma unroll
  for (int q = 0; q < 4; q++) ebA[q] = Efrag[(size_t)(t_first - 1) * 2560 + ebase + (size_t)q * 64];
#pragma unroll
  for (int q = 0; q < 4; q++) ebB[q] = Efrag[(size_t)t_first * 2560 + ebase + (size_t)q * 64];

  float llw = 0.f;

  auto step = [&](uint2 (&EB)[4], int ii) {
    // ---- phase a: Q = P (.) E (registers only)
    float qv[4][4];
#pragma unroll
    for (int q = 0; q < 4; q++) {
      half4 ev = h4_from_u2(EB[q]);
#pragma unroll
      for (int r = 0; r < 4; r++) qv[q][r] = Pa[q][r] * (float)ev[r];
    }
    // issue depth-2 prefetch for step ii+2 into the buffer just consumed
    {
      int tp = t_first + ii + 1; if (tp > t_last) tp = t_last;
#pragma unroll
      for (int q = 0; q < 4; q++) EB[q] = Efrag[(size_t)tp * 2560 + ebase + (size_t)q * 64];
    }
    // checkpoints: z[b] = sum_s Q[s][b]; lane sums its 16 states, quads via shfl
    if (ii == iw || ii == nstep) {
      float s = 0.f;
#pragma unroll
      for (int q = 0; q < 4; q++) s += (qv[q][0] + qv[q][1]) + (qv[q][2] + qv[q][3]);
      s += __shfl_xor(s, 16); s += __shfl_xor(s, 32);
      if (lane < 16) atomicAdd(&zslot[lane], s);
    }
    // write Q -> QL[cur]: 4 consecutive k-states per lane -> one b64 per tile
    int cur = ii & 1;
#pragma unroll
    for (int q = 0; q < 4; q++) {
      HU1 h0, h1, h2, h3;
      h0.h = (_Float16)qv[q][0]; h1.h = (_Float16)qv[q][1];
      h2.h = (_Float16)qv[q][2]; h3.h = (_Float16)qv[q][3];
      uint2 o; o.x = (uint32_t)h0.u | ((uint32_t)h1.u << 16);
      o.y = (uint32_t)h2.u | ((uint32_t)h3.u << 16);
      *(uint2*)&QL[cur][gl * QSTR + (w * 4 + q) * 16 + quad * 4] = o;
    }
    __syncthreads();   // the ONLY barrier per step
    if (ii == iw && tid < 16) { llw = logf(zslot[tid]); zslot[tid] = 0.f; }
    if (ii == nstep) {
      if (tid < 16) {
        float lle = logf(zslot[tid]);
        // CHL accounted steps between checkpoints, each carrying one x128
        atomicAdd(&out[bbase + tid], lle - llw - 32.0f * 4.852030263919617f);
      }
    } else {
      // ---- phase b: P^T = A^T @ Q^T (4 independent 10-deep MFMA chains)
      floatx4 a0 = (floatx4){0.f, 0.f, 0.f, 0.f};
      floatx4 a1 = a0, a2 = a0, a3 = a0;
#pragma unroll
      for (int kt = 0; kt < 10; kt++) {
        half8 qf = h8_from_u4(*(const uint4*)&QL[cur][gl * QSTR + kt * 32 + quad * 8]);
        a0 = __builtin_amdgcn_mfma_f32_16x16x32_f16(bfA[0][kt], qf, a0, 0, 0, 0);
        a1 = __builtin_amdgcn_mfma_f32_16x16x32_f16(bfA[1][kt], qf, a1, 0, 0, 0);
        a2 = __builtin_amdgcn_mfma_f32_16x16x32_f16(bfA[2][kt], qf, a2, 0, 0, 0);
        a3 = __builtin_amdgcn_mfma_f32_16x16x32_f16(bfA[3][kt], qf, a3, 0, 0, 0);
      }
#pragma unroll
      for (int r = 0; r < 4; r++) {
        Pa[0][r] = a0[r]; Pa[1][r] = a1[r]; Pa[2][r] = a2[r]; Pa[3][r] = a3[r];
      }
    }
  };

  // nstep is odd -> even number of sub-steps; ebA/ebB statically selected
  for (int i = 0; i <= nstep; i += 2) {
    step(ebA, i);
    step(ebB, i + 1);
  }
}

// ---- fallback (previous kernel) for small workspaces ----
__global__ __launch_bounds__(640, 3)
void hmm_fused(const uint32_t* __restrict__ Apk,
               const uint32_t* __restrict__ Bfr,
               const float* __restrict__ inp,
               const float* __restrict__ Ivec,
               float* __restrict__ out) {
  __shared__ __attribute__((aligned(16))) _Float16 inH[2][16 * FH];
  __shared__ __attribute__((aligned(16))) _Float16 QL[2][16 * QSTR];
  __shared__ float zslot[16];
  int c = blockIdx.x, bbase = blockIdx.y * 16;
  int tid = threadIdx.x, lane = tid & 63, w = tid >> 6;
  int gl = lane & 15, quad = lane >> 4;

  half8 bfA[2][10], bfB[2][4];
#pragma unroll
  for (int q = 0; q < 2; q++) {
#pragma unroll
    for (int kt = 0; kt < 10; kt++)
      bfA[q][kt] = h8_from_u4(((const uint4*)Apk)[((w * 2 + q) * 10 + kt) * 64 + lane]);
#pragma unroll
    for (int kt = 0; kt < 4; kt++)
      bfB[q][kt] = h8_from_u4(((const uint4*)Bfr)[((w * 2 + q) * 4 + kt) * 64 + lane]);
  }
#pragma unroll
  for (int q = 0; q < 2; q++) {
#pragma unroll
    for (int kt = 0; kt < 10; kt++) asm volatile("" : "+v"(bfA[q][kt]));
#pragma unroll
    for (int kt = 0; kt < 4; kt++)  asm volatile("" : "+v"(bfB[q][kt]));
  }

  float Pa[2][4];
#pragma unroll
  for (int q = 0; q < 2; q++) {
    int n = (w * 2 + q) * 16 + gl;
    float v = (n < S_DIM) ? (c == 0 ? Ivec[n] : 1.0f) : 0.f;
#pragma unroll
    for (int r = 0; r < 4; r++) Pa[q][r] = v;
  }
  if (tid < 16) zslot[tid] = 0.f;

  int t_first = (c == 0) ? 1 : (c * CHL - WARM + 1);
  int nstep   = (c == 0) ? (CHL - 1) : (CHL + WARM - 1);
  int iw      = (c == 0) ? -1 : (WARM - 1);
  int t_last  = t_first - 1 + nstep;

  {
    int t0 = t_first - 1;
#pragma unroll
    for (int s = 0; s < 2; s++) {
      int flat = tid + s * 640;
      if (flat < 1024) {
        int r = flat >> 6, c2 = flat & 63;
        float2 v; v.x = 0.f; v.y = 0.f;
        if (c2 < 63) v = *(const float2*)(inp + ((size_t)(bbase + r) * T_LEN + t0) * E_DIM + 2 * c2);
        HU1 a, b; a.h = (_Float16)v.x; b.h = (_Float16)v.y;
        *(uint32_t*)&inH[0][r * FH + 2 * c2] = (uint32_t)a.u | ((uint32_t)b.u << 16);
      }
    }
  }
  float2 g[2];
#pragma unroll
  for (int s = 0; s < 2; s++) {
    int flat = tid + s * 640;
    g[s].x = 0.f; g[s].y = 0.f;
    if (flat < 1024) {
      int r = flat >> 6, c2 = flat & 63;
      if (c2 < 63) g[s] = *(const float2*)(inp + ((size_t)(bbase + r) * T_LEN + t_first) * E_DIM + 2 * c2);
    }
  }
  float llw = 0.f;
  __syncthreads();

  for (int i = 0; i <= nstep; i++) {
    int cur = i & 1, nxt = cur ^ 1;
    floatx4 Ea0 = (floatx4){0.f, 0.f, 0.f, 0.f};
    floatx4 Ea1 = (floatx4){0.f, 0.f, 0.f, 0.f};
#pragma unroll
    for (int kt = 0; kt < 4; kt++) {
      half8 af = h8_from_u4(*(const uint4*)&inH[cur][gl * FH + kt * 32 + quad * 8]);
      Ea0 = __builtin_amdgcn_mfma_f32_16x16x32_f16(af, bfB[0][kt], Ea0, 0, 0, 0);
      Ea1 = __builtin_amdgcn_mfma_f32_16x16x32_f16(af, bfB[1][kt], Ea1, 0, 0, 0);
    }
    float qv[2][4];
#pragma unroll
    for (int r = 0; r < 4; r++) { qv[0][r] = Pa[0][r] * Ea0[r]; qv[1][r] = Pa[1][r] * Ea1[r]; }
    if (i == iw || i == nstep) {
      float s0 = qv[0][0] + qv[1][0], s1 = qv[0][1] + qv[1][1];
      float s2 = qv[0][2] + qv[1][2], s3 = qv[0][3] + qv[1][3];
#pragma unroll
      for (int off = 1; off <= 8; off <<= 1) {
        s0 += __shfl_xor(s0, off); s1 += __shfl_xor(s1, off);
        s2 += __shfl_xor(s2, off); s3 += __shfl_xor(s3, off);
      }
      if (gl == 0) {
        atomicAdd(&zslot[quad * 4 + 0], s0);
        atomicAdd(&zslot[quad * 4 + 1], s1);
        atomicAdd(&zslot[quad * 4 + 2], s2);
        atomicAdd(&zslot[quad * 4 + 3], s3);
      }
    }
#pragma unroll
    for (int q = 0; q < 2; q++) {
      int k = (w * 2 + q) * 16 + gl;
#pragma unroll
      for (int r = 0; r < 4; r++)
        QL[cur][(quad * 4 + r) * QSTR + k] = (_Float16)qv[q][r];
    }
    if (i < nstep) {
#pragma unroll
      for (int s = 0; s < 2; s++) {
        int flat = tid + s * 640;
        if (flat < 1024) {
          int r = flat >> 6, c2 = flat & 63;
          HU1 a, b; a.h = (_Float16)g[s].x; b.h = (_Float16)g[s].y;
          uint32_t pv = (c2 < 63) ? ((uint32_t)a.u | ((uint32_t)b.u << 16)) : 0u;
          *(uint32_t*)&inH[nxt][r * FH + 2 * c2] = pv;
        }
      }
    }
    __syncthreads();
    if (i == iw && tid < 16) { llw = logf(zslot[tid]); zslot[tid] = 0.f; }
    if (i == nstep) {
      if (tid < 16) {
        float lle = logf(zslot[tid]);
        atomicAdd(&out[bbase + tid], lle - llw - 32.0f * 4.852030263919617f);
      }
      break;
    }
    {
      int tp = t_first + i + 1; if (tp > t_last) tp = t_last;
#pragma unroll
      for (int s = 0; s < 2; s++) {
        int flat = tid + s * 640;
        g[s].x = 0.f; g[s].y = 0.f;
        if (flat < 1024) {
          int r = flat >> 6, c2 = flat & 63;
          if (c2 < 63) g[s] = *(const float2*)(inp + ((size_t)(bbase + r) * T_LEN + tp) * E_DIM + 2 * c2);
        }
      }
    }
    floatx4 acc0 = (floatx4){0.f, 0.f, 0.f, 0.f};
    floatx4 acc1 = (floatx4){0.f, 0.f, 0.f, 0.f};
#pragma unroll
    for (int kt = 0; kt < 10; kt++) {
      half8 afv = h8_from_u4(*(const uint4*)&QL[cur][gl * QSTR + kt * 32 + quad * 8]);
      acc0 = __builtin_amdgcn_mfma_f32_16x16x32_f16(afv, bfA[0][kt], acc0, 0, 0, 0);
      acc1 = __builtin_amdgcn_mfma_f32_16x16x32_f16(afv, bfA[1][kt], acc1, 0, 0, 0);
    }
#pragma unroll
    for (int r = 0; r < 4; r++) { Pa[0][r] = acc0[r]; Pa[1][r] = acc1[r]; }
  }
}

extern "C" void kernel_launch(void* const* d_in, const int* in_sizes, int n_in,
                              void* d_out, int out_size, void* d_ws, size_t ws_size,
                              hipStream_t stream) {
  const float* inp = (const float*)d_in[0];   // [32,4096,126]
  const float* A   = (const float*)d_in[1];   // [308,308]
  const float* Bm  = (const float*)d_in[2];   // [308,126]
  const float* Iv  = (const float*)d_in[3];   // [308]
  float* out = (float*)d_out;                 // [32]

  uint8_t* ws = (uint8_t*)d_ws;
  uint32_t* Apk = (uint32_t*)(ws);                 // 200 KiB
  uint32_t* Bfr = (uint32_t*)(ws + (256u << 10));  // 80 KiB
  const size_t EOFF   = (size_t)384 << 10;
  const size_t EBYTES = (size_t)T_LEN * 40 * 64 * sizeof(uint2);  // 80 MiB

  hipLaunchKernelGGL(init_pack, dim3(71), dim3(256), 0, stream, A, Bm, Apk, Bfr, out);
  if (ws_size >= EOFF + EBYTES) {
    uint2* Efrag = (uint2*)(ws + EOFF);
    hipLaunchKernelGGL(emis_pack, dim3(T_LEN / TC, 2), dim3(256), 0, stream, Bfr, inp, Efrag);
    hipLaunchKernelGGL(hmm_fused2, dim3(NCHUNK, NBATCH / 16), dim3(320), 0, stream,
                       Apk, Efrag, Iv, out);
  } else {
    hipLaunchKernelGGL(hmm_fused, dim3(NCHUNK, NBATCH / 16), dim3(640), 0, stream,
                       Apk, Bfr, inp, Iv, out);
  }
}